// Round 6
// baseline (569.111 us; speedup 1.0000x reference)
//
#include <hip/hip_runtime.h>

#define SEQ   16384
#define DIM   2048
#define CHUNK 128
#define NCHUNK (SEQ / CHUNK)   // 128

typedef __attribute__((ext_vector_type(8))) short  short8;
typedef __attribute__((ext_vector_type(4))) short  short4v;
typedef __attribute__((ext_vector_type(4))) float  floatx4;

static __device__ __forceinline__ float bf2f(short s) {
    return __uint_as_float(((unsigned)(unsigned short)s) << 16);
}
static __device__ __forceinline__ short f2bf(float f) {
    unsigned u = __float_as_uint(f);
    u += 0x7fff + ((u >> 16) & 1);   // RNE
    return (short)(u >> 16);
}

// ---------- fused fp32 -> bf16 cast for xs, w_in, c_out (one launch) ----------
// blocks [0, NB_XS) -> xs, [NB_XS, NB_XS+NB_W) -> w_in, rest -> c_out
#define NB_XS (SEQ * DIM / 4 / 256)     // 32768
#define NB_W  (DIM * DIM / 4 / 256)     // 4096
__global__ void cast3_kernel(const float* __restrict__ xs,   short* __restrict__ xs_o,
                             const float* __restrict__ w,    short* __restrict__ w_o,
                             const float* __restrict__ c,    short* __restrict__ c_o)
{
    int b = blockIdx.x;
    const float* in; short* out; int i;
    if (b < NB_XS)            { in = xs; out = xs_o; i = b * 256 + threadIdx.x; }
    else if (b < NB_XS + NB_W){ in = w;  out = w_o;  i = (b - NB_XS) * 256 + threadIdx.x; }
    else                      { in = c;  out = c_o;  i = (b - NB_XS - NB_W) * 256 + threadIdx.x; }
    float4 v = ((const float4*)in)[i];
    short4v s;
    s.x = f2bf(v.x); s.y = f2bf(v.y); s.z = f2bf(v.z); s.w = f2bf(v.w);
    ((short4v*)out)[i] = s;
}

// ---------- bf16 GEMM, C[m][n] = sum_k A[m][k]*B[n][k] (both K-contiguous) ----------
// 256x256 tile, BK=64, 512 threads = 8 waves (2M x 4N), wave => 128x64 output
// (quadrants mh in {0,1} row-halves, nh in {0,1} col-halves).
// EVEN-READ 4-phase-per-K-tile schedule: every MFMA's operands are ds_read
// exactly ONE phase ahead; reads per phase = 4/8/4/8 (never 12); stages
// front-loaded 2/2/0/0 per tile; counted vmcnt gates VMC2/VMC2/-/VMC1 (never
// 0 in the loop). XOR-8 slot swizzle both-sides (0 bank conflicts, verified).
// XCD-chunk block swizzle (FETCH 350->170 MB, verified R5).
// FUSE==0: store bf16 C. FUSE==1: store fp32 C + xs*dskip.

#define BAR   __builtin_amdgcn_s_barrier()
#define PRIO1 __builtin_amdgcn_s_setprio(1)
#define PRIO0 __builtin_amdgcn_s_setprio(0)
#define VMC2  asm volatile("s_waitcnt vmcnt(2)" ::: "memory")
#define VMC1  asm volatile("s_waitcnt vmcnt(1)" ::: "memory")
#define VMC0  asm volatile("s_waitcnt vmcnt(0)" ::: "memory")

// stage one 128x64 half-tile (16 KiB): 2 x global_load_lds(16B) per thread.
// LDS dest linear; global source slot XOR-swizzled (involution s^(row&7)).
#define STAGE_A(b, h, t) do { \
    const short* _s = Abase + (size_t)(h) * 128 * K + (size_t)(t) * 64; \
    __builtin_amdgcn_global_load_lds(_s + gOff0, &As[b][h][c0 * 8], 16, 0, 0); \
    __builtin_amdgcn_global_load_lds(_s + gOff1, &As[b][h][c1 * 8], 16, 0, 0); \
} while (0)
#define STAGE_B(b, h, t) do { \
    const short* _s = Bbase + (size_t)(h) * 128 * K + (size_t)(t) * 64; \
    __builtin_amdgcn_global_load_lds(_s + gOff0, &Bs[b][h][c0 * 8], 16, 0, 0); \
    __builtin_amdgcn_global_load_lds(_s + gOff1, &Bs[b][h][c1 * 8], 16, 0, 0); \
} while (0)

// fragment reads: logical slot (ks*4+quad), physical slot XOR (row&7) = sx
#define READ_A8(dst, b, mh) \
    _Pragma("unroll") \
    for (int mi = 0; mi < 4; mi++) { \
        _Pragma("unroll") \
        for (int ks = 0; ks < 2; ks++) \
            dst[mi][ks] = *(const short8*)&As[b][mh][(arow + mi * 16) * 64 + \
                                                     ((((ks << 2) | quad) ^ sx) << 3)]; \
    }
#define READ_B4(dst, b, nh) \
    _Pragma("unroll") \
    for (int ni = 0; ni < 2; ni++) { \
        _Pragma("unroll") \
        for (int ks = 0; ks < 2; ks++) \
            dst[ni][ks] = *(const short8*)&Bs[b][nh][(brow + ni * 16) * 64 + \
                                                     ((((ks << 2) | quad) ^ sx) << 3)]; \
    }
#define MMA(mh, nh, Aset, Bset) \
    _Pragma("unroll") \
    for (int mi = 0; mi < 4; mi++) { \
        _Pragma("unroll") \
        for (int ni = 0; ni < 2; ni++) { \
            acc[mh][nh][mi][ni] = __builtin_amdgcn_mfma_f32_16x16x32_bf16( \
                Aset[mi][0], Bset[ni][0], acc[mh][nh][mi][ni], 0, 0, 0); \
            acc[mh][nh][mi][ni] = __builtin_amdgcn_mfma_f32_16x16x32_bf16( \
                Aset[mi][1], Bset[ni][1], acc[mh][nh][mi][ni], 0, 0, 0); \
        } \
    }

template<int FUSE>
__global__ __launch_bounds__(512, 2)
void gemm_bt(const short* __restrict__ A, const short* __restrict__ B,
             short* __restrict__ Cbf, float* __restrict__ Cf,
             const float* __restrict__ xs, const float* __restrict__ dskip)
{
    constexpr int K  = DIM;        // 2048
    constexpr int NT = K / 64;     // 32 K-tiles

    __shared__ alignas(16) short As[2][2][128 * 64];   // [buf][half][row*64+slot*8]
    __shared__ alignas(16) short Bs[2][2][128 * 64];

    const int tid = threadIdx.x;
    // XCD-chunk swizzle (bijective on the 8x64 grid): hw xcd = raw%8 owns an
    // 8x8 super-tile (rows 8*xcd..8*xcd+7, all 8 cols).
    const int raw  = blockIdx.y * gridDim.x + blockIdx.x;
    const int xcd  = raw & 7;
    const int slot = raw >> 3;                 // 0..63
    const int m0   = ((xcd << 3) | (slot >> 3)) * 256;
    const int n0   = (slot & 7) * 256;

    const int lane = tid & 63;
    const int wv   = tid >> 6;
    const int wrow = wv >> 2;           // 0..1
    const int wcol = wv & 3;            // 0..3
    const int l16  = lane & 15;
    const int quad = lane >> 4;
    const int sx   = l16 & 7;
    const int arow = wrow * 64 + l16;   // local row in A half-region
    const int brow = wcol * 32 + l16;   // local row in B half-region

    // staging constants: chunks c0, c1 of each half-tile (1024 x 16B chunks)
    const int c0 = tid, c1 = tid + 512;
    const int r0 = c0 >> 3, r1 = c1 >> 3;
    const size_t gOff0 = (size_t)r0 * K + (size_t)((((c0 & 7) ^ (r0 & 7))) * 8);
    const size_t gOff1 = (size_t)r1 * K + (size_t)((((c1 & 7) ^ (r1 & 7))) * 8);
    const short* Abase = A + (size_t)m0 * K;
    const short* Bbase = B + (size_t)n0 * K;

    short8  aE[4][2], aO[4][2], bE[2][2], bO[2][2];
    floatx4 acc[2][2][4][2] = {};   // [mh][nh][mi][ni]

    // ---- prologue: buf0 <- tile0. Order {Ah0,Bh0,Bh1} then Ah1; drain first 3.
    STAGE_A(0, 0, 0); STAGE_B(0, 0, 0); STAGE_B(0, 1, 0);
    STAGE_A(0, 1, 0);
    VMC1;                    // queue: {Ah1(0)}  == steady-state entry invariant
    BAR;
    READ_A8(aE, 0, 0); READ_B4(bE, 0, 0);   // pre-read tile0 quadrant(0,0) operands

    for (int i = 0; i < NT / 2; ++i) {
        const int t1 = 2 * i + 1;
        const int t2 = (2 * i + 2) & (NT - 1);   // wrap: tail stages harmless

        // ======== tile even (buf0); stages -> buf1 <- t1 ========
        // p0: mma(0,0); read bO (Bh1, cur); stage Ah0,Bh0(next). VMC2 drains Ah1(cur).
        READ_B4(bO, 0, 1);
        STAGE_A(1, 0, t1); STAGE_B(1, 0, t1);
        PRIO1; MMA(0, 0, aE, bE); PRIO0;
        VMC2;
        BAR;
        // p1: mma(0,1); read aO (Ah1, cur); stage Bh1,Ah1(next). VMC2 drains Ah0,Bh0(next).
        READ_A8(aO, 0, 1);
        STAGE_B(1, 1, t1); STAGE_A(1, 1, t1);
        PRIO1; MMA(0, 1, aE, bO); PRIO0;
        VMC2;
        BAR;
        // p2: mma(1,0); then re-read bE from NEXT buf (Bh0(next), gated at p1).
        PRIO1; MMA(1, 0, aO, bE); PRIO0;
        READ_B4(bE, 1, 0);
        BAR;
        // p3: mma(1,1); re-read aE from NEXT buf (Ah0(next), gated at p1).
        //     VMC1 drains Bh1(next), leaves Ah1(next) in flight (entry invariant).
        PRIO1; MMA(1, 1, aO, bO); PRIO0;
        READ_A8(aE, 1, 0);
        VMC1;
        BAR;

        // ======== tile odd (buf1); stages -> buf0 <- t2 ========
        READ_B4(bO, 1, 1);
        STAGE_A(0, 0, t2); STAGE_B(0, 0, t2);
        PRIO1; MMA(0, 0, aE, bE); PRIO0;
        VMC2;
        BAR;

        READ_A8(aO, 1, 1);
        STAGE_B(0, 1, t2); STAGE_A(0, 1, t2);
        PRIO1; MMA(0, 1, aE, bO); PRIO0;
        VMC2;
        BAR;

        PRIO1; MMA(1, 0, aO, bE); PRIO0;
        READ_B4(bE, 0, 0);
        BAR;

        PRIO1; MMA(1, 1, aO, bO); PRIO0;
        READ_A8(aE, 0, 0);
        VMC1;
        BAR;
    }
    VMC0;   // no LDS-DMA may outlive this workgroup

    // ---- epilogue: C row = m0+wrow*64+mh*128+mi*16+quad*4+r, col = n0+wcol*32+nh*128+ni*16+l16
    if (FUSE == 0) {
        #pragma unroll
        for (int mh = 0; mh < 2; mh++)
        #pragma unroll
        for (int mi = 0; mi < 4; mi++) {
            const int rb = m0 + wrow * 64 + mh * 128 + mi * 16 + quad * 4;
            #pragma unroll
            for (int nh = 0; nh < 2; nh++)
            #pragma unroll
            for (int ni = 0; ni < 2; ni++) {
                const int cc = n0 + wcol * 32 + nh * 128 + ni * 16 + l16;
                #pragma unroll
                for (int r = 0; r < 4; r++)
                    Cbf[(size_t)(rb + r) * DIM + cc] = f2bf(acc[mh][nh][mi][ni][r]);
            }
        }
    } else {
        float dsk[2][2];
        #pragma unroll
        for (int nh = 0; nh < 2; nh++)
        #pragma unroll
        for (int ni = 0; ni < 2; ni++)
            dsk[nh][ni] = dskip[n0 + wcol * 32 + nh * 128 + ni * 16 + l16];
        #pragma unroll
        for (int mh = 0; mh < 2; mh++)
        #pragma unroll
        for (int mi = 0; mi < 4; mi++) {
            const int rb = m0 + wrow * 64 + mh * 128 + mi * 16 + quad * 4;
            #pragma unroll
            for (int nh = 0; nh < 2; nh++)
            #pragma unroll
            for (int ni = 0; ni < 2; ni++) {
                const int cc = n0 + wcol * 32 + nh * 128 + ni * 16 + l16;
                #pragma unroll
                for (int r = 0; r < 4; r++) {
                    size_t idx = (size_t)(rb + r) * DIM + cc;
                    Cf[idx] = acc[mh][nh][mi][ni][r] + xs[idx] * dsk[nh][ni];
                }
            }
        }
    }
}

// ---------- scan pass 1: per-chunk local final state (zero init), 4 cols/thread ----------
__global__ void scan_pass1(const short* __restrict__ bx, const float* __restrict__ lam,
                           float* __restrict__ blockLast)
{
    int q     = blockIdx.x * 256 + threadIdx.x;   // 4-col group id, q < DIM/4
    int n     = q * 4;
    int chunk = blockIdx.y;
    float4 lm = *(const float4*)&lam[n];
    const uint2* p = (const uint2*)(bx + (size_t)chunk * CHUNK * DIM) + q;
    float h0 = 0.f, h1 = 0.f, h2 = 0.f, h3 = 0.f;
    #pragma unroll 16
    for (int i = 0; i < CHUNK; i++) {
        uint2 v = p[(size_t)i * (DIM / 4)];
        h0 = fmaf(lm.x, h0, bf2f((short)(v.x & 0xffffu)));
        h1 = fmaf(lm.y, h1, bf2f((short)(v.x >> 16)));
        h2 = fmaf(lm.z, h2, bf2f((short)(v.y & 0xffffu)));
        h3 = fmaf(lm.w, h3, bf2f((short)(v.y >> 16)));
    }
    float4 o; o.x = h0; o.y = h1; o.z = h2; o.w = h3;
    *(float4*)&blockLast[(size_t)chunk * DIM + n] = o;
}

// ---------- scan pass 2: exclusive prefix over chunks (in place), 1 col/thread ----------
__global__ void scan_pass2(float* __restrict__ blockLast, const float* __restrict__ lam)
{
    int n = blockIdx.x * 256 + threadIdx.x;
    float lm = lam[n];
    float p = lm;
    #pragma unroll
    for (int i = 0; i < 7; i++) p = p * p;    // lam^128
    float carry = 0.f;
    #pragma unroll 4
    for (int c = 0; c < NCHUNK; c++) {
        float t = blockLast[(size_t)c * DIM + n];
        blockLast[(size_t)c * DIM + n] = carry;
        carry = fmaf(p, carry, t);
    }
}

// ---------- scan pass 3: apply carry, write hs (bf16, in place over bx), 4 cols/thread ----------
__global__ void scan_pass3(short* __restrict__ bxh, const float* __restrict__ lam,
                           const float* __restrict__ carry)
{
    int q     = blockIdx.x * 256 + threadIdx.x;
    int n     = q * 4;
    int chunk = blockIdx.y;
    float4 lm = *(const float4*)&lam[n];
    float4 cv = *(const float4*)&carry[(size_t)chunk * DIM + n];
    float h0 = cv.x, h1 = cv.y, h2 = cv.z, h3 = cv.w;
    uint2* p = (uint2*)(bxh + (size_t)chunk * CHUNK * DIM) + q;
    #pragma unroll 16
    for (int i = 0; i < CHUNK; i++) {
        uint2 v = p[(size_t)i * (DIM / 4)];
        h0 = fmaf(lm.x, h0, bf2f((short)(v.x & 0xffffu)));
        h1 = fmaf(lm.y, h1, bf2f((short)(v.x >> 16)));
        h2 = fmaf(lm.z, h2, bf2f((short)(v.y & 0xffffu)));
        h3 = fmaf(lm.w, h3, bf2f((short)(v.y >> 16)));
        uint2 o;
        o.x = (unsigned)(unsigned short)f2bf(h0) | ((unsigned)(unsigned short)f2bf(h1) << 16);
        o.y = (unsigned)(unsigned short)f2bf(h2) | ((unsigned)(unsigned short)f2bf(h3) << 16);
        p[(size_t)i * (DIM / 4)] = o;
    }
}

extern "C" void kernel_launch(void* const* d_in, const int* in_sizes, int n_in,
                              void* d_out, int out_size, void* d_ws, size_t ws_size,
                              hipStream_t stream)
{
    const float* xs    = (const float*)d_in[0];
    const float* lam   = (const float*)d_in[1];
    const float* w_in  = (const float*)d_in[2];
    const float* c_out = (const float*)d_in[3];
    const float* dskip = (const float*)d_in[4];
    float* out = (float*)d_out;

    // ws layout:
    //   [0,   64M) : bx / hs  bf16  [SEQ][DIM]
    //   [64M, 72M) : w_in     bf16  [DIM][DIM]
    //   [72M, 80M) : c_out    bf16  [DIM][DIM]
    char*  ws    = (char*)d_ws;
    short* bxh   = (short*)ws;
    short* w_bf  = (short*)(ws + (size_t)64 * 1024 * 1024);
    short* c_bf  = (short*)(ws + (size_t)72 * 1024 * 1024);
    // xs_bf16 in front 64 MiB of d_out (dead before final GEMM writes it);
    // chunk carries (1 MiB) at d_out+100 MiB (also dead until final GEMM write).
    short* xs_bf = (short*)d_out;
    float* blkl  = (float*)((char*)d_out + (size_t)100 * 1024 * 1024);

    cast3_kernel<<<NB_XS + 2 * NB_W, 256, 0, stream>>>(xs, xs_bf, w_in, w_bf, c_out, c_bf);

    dim3 ggrid(DIM / 256, SEQ / 256);   // (8, 64)
    gemm_bt<0><<<ggrid, 512, 0, stream>>>(xs_bf, w_bf, bxh, nullptr, nullptr, nullptr);

    dim3 sgrid(DIM / 1024, NCHUNK);     // (2, 128)
    scan_pass1<<<sgrid, 256, 0, stream>>>(bxh, lam, blkl);
    scan_pass2<<<DIM / 256, 256, 0, stream>>>(blkl, lam);
    scan_pass3<<<sgrid, 256, 0, stream>>>(bxh, lam, blkl);

    gemm_bt<1><<<ggrid, 512, 0, stream>>>(bxh, c_bf, nullptr, out, xs, dskip);
}

// Round 7
// 562.767 us; speedup vs baseline: 1.0113x; 1.0113x over previous
//
#include <hip/hip_runtime.h>

#define SEQ   16384
#define DIM   2048
#define CHUNK 128
#define NCHUNK (SEQ / CHUNK)   // 128

typedef __attribute__((ext_vector_type(8))) short  short8;
typedef __attribute__((ext_vector_type(4))) short  short4v;
typedef __attribute__((ext_vector_type(4))) float  floatx4;

static __device__ __forceinline__ float bf2f(short s) {
    return __uint_as_float(((unsigned)(unsigned short)s) << 16);
}
static __device__ __forceinline__ short f2bf(float f) {
    unsigned u = __float_as_uint(f);
    u += 0x7fff + ((u >> 16) & 1);   // RNE
    return (short)(u >> 16);
}

// ---------- fused fp32 -> bf16 cast for xs, w_in, c_out (one launch) ----------
#define NB_XS (SEQ * DIM / 4 / 256)     // 32768
#define NB_W  (DIM * DIM / 4 / 256)     // 4096
__global__ void cast3_kernel(const float* __restrict__ xs,   short* __restrict__ xs_o,
                             const float* __restrict__ w,    short* __restrict__ w_o,
                             const float* __restrict__ c,    short* __restrict__ c_o)
{
    int b = blockIdx.x;
    const float* in; short* out; int i;
    if (b < NB_XS)            { in = xs; out = xs_o; i = b * 256 + threadIdx.x; }
    else if (b < NB_XS + NB_W){ in = w;  out = w_o;  i = (b - NB_XS) * 256 + threadIdx.x; }
    else                      { in = c;  out = c_o;  i = (b - NB_XS - NB_W) * 256 + threadIdx.x; }
    float4 v = ((const float4*)in)[i];
    short4v s;
    s.x = f2bf(v.x); s.y = f2bf(v.y); s.z = f2bf(v.z); s.w = f2bf(v.w);
    ((short4v*)out)[i] = s;
}

// ---------- bf16 GEMM, C[m][n] = sum_k A[m][k]*B[n][k] (both K-contiguous) ----------
// 256x256 tile, BK=64, 512 threads = 8 waves (2M x 4N), wave => 128x64 output
// (quadrant layout: rows wrow*64 + mh*128 + mi*16 + quad*4 + r,
//                   cols wcol*32 + nh*128 + ni*16 + l16).
// SPARSE-GATE pipelined schedule: per K-tile 4 phases, MFMA order
// (0,0),(1,0),(0,1),(1,1); each operand ds_read exactly ONE phase before use
// (reads/phase = 8/4/4/8, single register set per operand); ALL 8 stage
// instructions issued once per tile at p2 in order [Bh0,Ah0,Ah1,Bh1]; counted
// gates VMC10/VMC8/VMC6/VMC12 each wait only on DMA issued >=4 phases
// (~1400 cyc) earlier -- never on young loads (R6's per-phase tight gates
// stalled every phase). XOR-8 slot swizzle both-sides (0 conflicts, verified).
// XCD-chunk block swizzle (FETCH 350->170 MB, verified R5).
// FUSE==0: store bf16 C + FUSED scan_pass1 (per-chunk weighted sums from fp32
// acc -> blockLast). FUSE==1: store fp32 C + xs*dskip.

#define BAR   __builtin_amdgcn_s_barrier()
#define PRIO1 __builtin_amdgcn_s_setprio(1)
#define PRIO0 __builtin_amdgcn_s_setprio(0)
#define VMC12 asm volatile("s_waitcnt vmcnt(12)" ::: "memory")
#define VMC10 asm volatile("s_waitcnt vmcnt(10)" ::: "memory")
#define VMC8  asm volatile("s_waitcnt vmcnt(8)" ::: "memory")
#define VMC6  asm volatile("s_waitcnt vmcnt(6)" ::: "memory")
#define VMC0  asm volatile("s_waitcnt vmcnt(0)" ::: "memory")

// stage one 128x64 half-tile (16 KiB): 2 x global_load_lds(16B) per thread.
// LDS dest linear; global source slot XOR-swizzled (involution s^(row&7)).
#define STAGE_A(b, h, t) do { \
    const short* _s = Abase + (size_t)(h) * 128 * K + (size_t)(t) * 64; \
    __builtin_amdgcn_global_load_lds(_s + gOff0, &As[b][h][c0 * 8], 16, 0, 0); \
    __builtin_amdgcn_global_load_lds(_s + gOff1, &As[b][h][c1 * 8], 16, 0, 0); \
} while (0)
#define STAGE_B(b, h, t) do { \
    const short* _s = Bbase + (size_t)(h) * 128 * K + (size_t)(t) * 64; \
    __builtin_amdgcn_global_load_lds(_s + gOff0, &Bs[b][h][c0 * 8], 16, 0, 0); \
    __builtin_amdgcn_global_load_lds(_s + gOff1, &Bs[b][h][c1 * 8], 16, 0, 0); \
} while (0)

// fragment reads: logical slot (ks*4+quad), physical slot XOR (row&7) = sx
#define READ_A8(dst, b, mh) \
    _Pragma("unroll") \
    for (int mi = 0; mi < 4; mi++) { \
        _Pragma("unroll") \
        for (int ks = 0; ks < 2; ks++) \
            dst[mi][ks] = *(const short8*)&As[b][mh][(arow + mi * 16) * 64 + \
                                                     ((((ks << 2) | quad) ^ sx) << 3)]; \
    }
#define READ_B4(dst, b, nh) \
    _Pragma("unroll") \
    for (int ni = 0; ni < 2; ni++) { \
        _Pragma("unroll") \
        for (int ks = 0; ks < 2; ks++) \
            dst[ni][ks] = *(const short8*)&Bs[b][nh][(brow + ni * 16) * 64 + \
                                                     ((((ks << 2) | quad) ^ sx) << 3)]; \
    }
#define MMA(mh, nh, Aset, Bset) \
    _Pragma("unroll") \
    for (int mi = 0; mi < 4; mi++) { \
        _Pragma("unroll") \
        for (int ni = 0; ni < 2; ni++) { \
            acc[mh][nh][mi][ni] = __builtin_amdgcn_mfma_f32_16x16x32_bf16( \
                Aset[mi][0], Bset[ni][0], acc[mh][nh][mi][ni], 0, 0, 0); \
            acc[mh][nh][mi][ni] = __builtin_amdgcn_mfma_f32_16x16x32_bf16( \
                Aset[mi][1], Bset[ni][1], acc[mh][nh][mi][ni], 0, 0, 0); \
        } \
    }

template<int FUSE>
__global__ __launch_bounds__(512, 2)
void gemm_bt(const short* __restrict__ A, const short* __restrict__ B,
             short* __restrict__ Cbf, float* __restrict__ Cf,
             const float* __restrict__ xs, const float* __restrict__ dskip,
             const float* __restrict__ lamv, float* __restrict__ blkl)
{
    constexpr int K  = DIM;        // 2048
    constexpr int NT = K / 64;     // 32 K-tiles

    __shared__ alignas(16) short As[2][2][128 * 64];   // [buf][half][row*64+slot*8]
    __shared__ alignas(16) short Bs[2][2][128 * 64];

    const int tid = threadIdx.x;
    // XCD-chunk swizzle (bijective on the 8x64 grid): hw xcd = raw%8 owns an
    // 8x8 super-tile (rows 8*xcd..8*xcd+7, all 8 cols).
    const int raw  = blockIdx.y * gridDim.x + blockIdx.x;
    const int xcd  = raw & 7;
    const int slot = raw >> 3;                 // 0..63
    const int m0   = ((xcd << 3) | (slot >> 3)) * 256;
    const int n0   = (slot & 7) * 256;

    const int lane = tid & 63;
    const int wv   = tid >> 6;
    const int wrow = wv >> 2;           // 0..1
    const int wcol = wv & 3;            // 0..3
    const int l16  = lane & 15;
    const int quad = lane >> 4;
    const int sx   = l16 & 7;
    const int arow = wrow * 64 + l16;   // local row in A half-region
    const int brow = wcol * 32 + l16;   // local row in B half-region

    // staging constants: chunks c0, c1 of each half-tile (1024 x 16B chunks)
    const int c0 = tid, c1 = tid + 512;
    const int r0 = c0 >> 3, r1 = c1 >> 3;
    const size_t gOff0 = (size_t)r0 * K + (size_t)((((c0 & 7) ^ (r0 & 7))) * 8);
    const size_t gOff1 = (size_t)r1 * K + (size_t)((((c1 & 7) ^ (r1 & 7))) * 8);
    const short* Abase = A + (size_t)m0 * K;
    const short* Bbase = B + (size_t)n0 * K;

    short8  A0v[4][2], A1v[4][2], B0v[2][2], B1v[2][2];
    floatx4 acc[2][2][4][2] = {};   // [mh][nh][mi][ni]

    // ---- prologue: tile0 -> buf0 (any order); tile1 -> buf1 ORDER [Bh0,Ah0,Ah1,Bh1]
    STAGE_A(0, 0, 0); STAGE_A(0, 1, 0); STAGE_B(0, 0, 0); STAGE_B(0, 1, 0);
    STAGE_B(1, 0, 1); STAGE_A(1, 0, 1); STAGE_A(1, 1, 1); STAGE_B(1, 1, 1);
    VMC8;            // tile0 fully landed (tile1's 8 may remain in flight)
    BAR;
    READ_B4(B0v, 0, 0);              // tile0 Bh0  (used p0,p1 of tile0)
    READ_A8(A0v, 0, 0);              // tile0 Ah0  (used p0,p2 of tile0)

    #pragma unroll 1
    for (int i = 0; i < NT / 2; ++i) {
        const bool more = (i < NT / 2 - 1);
        const int tE = 2 * i + 2;    // staged at even-p2 -> buf0
        const int tO = 2 * i + 3;    // staged at odd-p2  -> buf1

        // ======== tile even (buf0); next-tile reads from buf1 ========
        // p0: gate Ah1(cur) [staged >=4 phases ago]
        VMC10; READ_A8(A1v, 0, 1);
        PRIO1; MMA(0, 0, A0v, B0v); PRIO0; BAR;
        // p1: gate Bh1(cur)
        VMC8;  READ_B4(B1v, 0, 1);
        PRIO1; MMA(1, 0, A1v, B0v); PRIO0; BAR;
        // p2: gate Bh0(next, staged 4 phases ago); read it; issue 8 stages for t+2
        VMC6;  READ_B4(B0v, 1, 0);
        if (more) { STAGE_B(0, 0, tE); STAGE_A(0, 0, tE); STAGE_A(0, 1, tE); STAGE_B(0, 1, tE); }
        PRIO1; MMA(0, 1, A0v, B1v); PRIO0; BAR;
        // p3: gate Ah0(next)
        VMC12; READ_A8(A0v, 1, 0);
        PRIO1; MMA(1, 1, A1v, B1v); PRIO0; BAR;

        // ======== tile odd (buf1); next-tile reads from buf0 ========
        VMC10; READ_A8(A1v, 1, 1);
        PRIO1; MMA(0, 0, A0v, B0v); PRIO0; BAR;

        VMC8;  READ_B4(B1v, 1, 1);
        PRIO1; MMA(1, 0, A1v, B0v); PRIO0; BAR;

        VMC6;
        if (more) { READ_B4(B0v, 0, 0); }
        if (more) { STAGE_B(1, 0, tO); STAGE_A(1, 0, tO); STAGE_A(1, 1, tO); STAGE_B(1, 1, tO); }
        PRIO1; MMA(0, 1, A0v, B1v); PRIO0; BAR;

        VMC12;
        if (more) { READ_A8(A0v, 0, 0); }
        PRIO1; MMA(1, 1, A1v, B1v); PRIO0; BAR;
    }
    VMC0;   // no LDS-DMA may outlive this workgroup

    // ---- epilogue: C row = m0+wrow*64+mh*128+mi*16+quad*4+r, col = n0+wcol*32+nh*128+ni*16+l16
    if (FUSE == 0) {
        #pragma unroll
        for (int mh = 0; mh < 2; mh++)
        #pragma unroll
        for (int mi = 0; mi < 4; mi++) {
            const int rb = m0 + wrow * 64 + mh * 128 + mi * 16 + quad * 4;
            #pragma unroll
            for (int nh = 0; nh < 2; nh++)
            #pragma unroll
            for (int ni = 0; ni < 2; ni++) {
                const int cc = n0 + wcol * 32 + nh * 128 + ni * 16 + l16;
                #pragma unroll
                for (int r = 0; r < 4; r++)
                    Cbf[(size_t)(rb + r) * DIM + cc] = f2bf(acc[mh][nh][mi][ni][r]);
            }
        }
        // ---- fused scan_pass1: blockLast[chunk][col] = sum_i lam^(127-i) * acc
        // chunk = m0/128 + mh; row-in-chunk = wrow*64 + mi*16 + quad*4 + r.
        // weight = lam^(127-row) = (l^4)^(k3 + 4*(3-mi)) * l^(3-r),
        // k3 = 19 - 16*wrow - quad  (>= 0).
        float Pacc[2][2][2];   // [mh][nh][ni]
        #pragma unroll
        for (int nh = 0; nh < 2; nh++)
        #pragma unroll
        for (int ni = 0; ni < 2; ni++) {
            const int cc = n0 + wcol * 32 + nh * 128 + ni * 16 + l16;
            const float l = lamv[cc];
            const float l2 = l * l, l4 = l2 * l2, l8 = l4 * l4;
            const float l16p = l8 * l8, l32 = l16p * l16p, l64 = l32 * l32;
            const int k3 = 19 - 16 * wrow - quad;
            float q = 1.f;
            q = (k3 & 1)  ? q * l4   : q;
            q = (k3 & 2)  ? q * l8   : q;
            q = (k3 & 4)  ? q * l16p : q;
            q = (k3 & 8)  ? q * l32  : q;
            q = (k3 & 16) ? q * l64  : q;
            #pragma unroll
            for (int mh = 0; mh < 2; mh++) {
                float s = 0.f, qq = q;
                #pragma unroll
                for (int mi = 3; mi >= 0; --mi) {
                    floatx4 a = acc[mh][nh][mi][ni];
                    float inner = fmaf(fmaf(fmaf(a[0], l, a[1]), l, a[2]), l, a[3]);
                    s = fmaf(qq, inner, s);
                    qq *= l16p;
                }
                Pacc[mh][nh][ni] = s;
            }
        }
        // cross-quad (shfl) then cross-wave (LDS) reduction
        float* Pl = (float*)&As[0][0][0];    // [wrow][mh][256 cols], 4 KB
        #pragma unroll
        for (int mh = 0; mh < 2; mh++)
        #pragma unroll
        for (int nh = 0; nh < 2; nh++)
        #pragma unroll
        for (int ni = 0; ni < 2; ni++) {
            float v = Pacc[mh][nh][ni];
            v += __shfl_xor(v, 16);
            v += __shfl_xor(v, 32);
            if (lane < 16)
                Pl[wrow * 512 + mh * 256 + (wcol * 32 + nh * 128 + ni * 16 + l16)] = v;
        }
        __syncthreads();
        {
            const int mh = tid >> 8, cl = tid & 255;
            float v = Pl[mh * 256 + cl] + Pl[512 + mh * 256 + cl];
            blkl[(size_t)((m0 >> 7) + mh) * DIM + (n0 + cl)] = v;
        }
    } else {
        float dsk[2][2];
        #pragma unroll
        for (int nh = 0; nh < 2; nh++)
        #pragma unroll
        for (int ni = 0; ni < 2; ni++)
            dsk[nh][ni] = dskip[n0 + wcol * 32 + nh * 128 + ni * 16 + l16];
        #pragma unroll
        for (int mh = 0; mh < 2; mh++)
        #pragma unroll
        for (int mi = 0; mi < 4; mi++) {
            const int rb = m0 + wrow * 64 + mh * 128 + mi * 16 + quad * 4;
            #pragma unroll
            for (int nh = 0; nh < 2; nh++)
            #pragma unroll
            for (int ni = 0; ni < 2; ni++) {
                const int cc = n0 + wcol * 32 + nh * 128 + ni * 16 + l16;
                #pragma unroll
                for (int r = 0; r < 4; r++) {
                    size_t idx = (size_t)(rb + r) * DIM + cc;
                    Cf[idx] = acc[mh][nh][mi][ni][r] + xs[idx] * dsk[nh][ni];
                }
            }
        }
    }
}

// ---------- scan pass 2: exclusive prefix over chunks (in place), 1 col/thread ----------
__global__ void scan_pass2(float* __restrict__ blockLast, const float* __restrict__ lam)
{
    int n = blockIdx.x * 256 + threadIdx.x;
    float lm = lam[n];
    float p = lm;
    #pragma unroll
    for (int i = 0; i < 7; i++) p = p * p;    // lam^128
    float carry = 0.f;
    #pragma unroll 4
    for (int c = 0; c < NCHUNK; c++) {
        float t = blockLast[(size_t)c * DIM + n];
        blockLast[(size_t)c * DIM + n] = carry;
        carry = fmaf(p, carry, t);
    }
}

// ---------- scan pass 3: apply carry, write hs (bf16, in place over bx), 4 cols/thread ----------
__global__ void scan_pass3(short* __restrict__ bxh, const float* __restrict__ lam,
                           const float* __restrict__ carry)
{
    int q     = blockIdx.x * 256 + threadIdx.x;
    int n     = q * 4;
    int chunk = blockIdx.y;
    float4 lm = *(const float4*)&lam[n];
    float4 cv = *(const float4*)&carry[(size_t)chunk * DIM + n];
    float h0 = cv.x, h1 = cv.y, h2 = cv.z, h3 = cv.w;
    uint2* p = (uint2*)(bxh + (size_t)chunk * CHUNK * DIM) + q;
    #pragma unroll 16
    for (int i = 0; i < CHUNK; i++) {
        uint2 v = p[(size_t)i * (DIM / 4)];
        h0 = fmaf(lm.x, h0, bf2f((short)(v.x & 0xffffu)));
        h1 = fmaf(lm.y, h1, bf2f((short)(v.x >> 16)));
        h2 = fmaf(lm.z, h2, bf2f((short)(v.y & 0xffffu)));
        h3 = fmaf(lm.w, h3, bf2f((short)(v.y >> 16)));
        uint2 o;
        o.x = (unsigned)(unsigned short)f2bf(h0) | ((unsigned)(unsigned short)f2bf(h1) << 16);
        o.y = (unsigned)(unsigned short)f2bf(h2) | ((unsigned)(unsigned short)f2bf(h3) << 16);
        p[(size_t)i * (DIM / 4)] = o;
    }
}

extern "C" void kernel_launch(void* const* d_in, const int* in_sizes, int n_in,
                              void* d_out, int out_size, void* d_ws, size_t ws_size,
                              hipStream_t stream)
{
    const float* xs    = (const float*)d_in[0];
    const float* lam   = (const float*)d_in[1];
    const float* w_in  = (const float*)d_in[2];
    const float* c_out = (const float*)d_in[3];
    const float* dskip = (const float*)d_in[4];
    float* out = (float*)d_out;

    // ws layout:
    //   [0,   64M) : bx / hs  bf16  [SEQ][DIM]
    //   [64M, 72M) : w_in     bf16  [DIM][DIM]
    //   [72M, 80M) : c_out    bf16  [DIM][DIM]
    char*  ws    = (char*)d_ws;
    short* bxh   = (short*)ws;
    short* w_bf  = (short*)(ws + (size_t)64 * 1024 * 1024);
    short* c_bf  = (short*)(ws + (size_t)72 * 1024 * 1024);
    // xs_bf16 in front 64 MiB of d_out (dead before final GEMM writes it);
    // chunk carries (1 MiB) at d_out+100 MiB (dead until final GEMM write).
    short* xs_bf = (short*)d_out;
    float* blkl  = (float*)((char*)d_out + (size_t)100 * 1024 * 1024);

    cast3_kernel<<<NB_XS + 2 * NB_W, 256, 0, stream>>>(xs, xs_bf, w_in, w_bf, c_out, c_bf);

    dim3 ggrid(DIM / 256, SEQ / 256);   // (8, 64)
    gemm_bt<0><<<ggrid, 512, 0, stream>>>(xs_bf, w_bf, bxh, nullptr, nullptr, nullptr,
                                          lam, blkl);

    scan_pass2<<<DIM / 256, 256, 0, stream>>>(blkl, lam);
    dim3 sgrid(DIM / 1024, NCHUNK);     // (2, 128)
    scan_pass3<<<sgrid, 256, 0, stream>>>(bxh, lam, blkl);

    gemm_bt<1><<<ggrid, 512, 0, stream>>>(bxh, c_bf, nullptr, out, xs, dskip,
                                          nullptr, nullptr);
}

// Round 8
// 547.714 us; speedup vs baseline: 1.0391x; 1.0275x over previous
//
#include <hip/hip_runtime.h>

#define SEQ   16384
#define DIM   2048
#define CHUNK 128
#define NCHUNK (SEQ / CHUNK)   // 128

typedef __attribute__((ext_vector_type(8))) short  short8;
typedef __attribute__((ext_vector_type(4))) short  short4v;
typedef __attribute__((ext_vector_type(4))) float  floatx4;

static __device__ __forceinline__ float bf2f(short s) {
    return __uint_as_float(((unsigned)(unsigned short)s) << 16);
}
static __device__ __forceinline__ short f2bf(float f) {
    unsigned u = __float_as_uint(f);
    u += 0x7fff + ((u >> 16) & 1);   // RNE
    return (short)(u >> 16);
}

// ---------- fused fp32 -> bf16 cast for xs, w_in, c_out (one launch) ----------
#define NB_XS (SEQ * DIM / 4 / 256)     // 32768
#define NB_W  (DIM * DIM / 4 / 256)     // 4096
__global__ void cast3_kernel(const float* __restrict__ xs,   short* __restrict__ xs_o,
                             const float* __restrict__ w,    short* __restrict__ w_o,
                             const float* __restrict__ c,    short* __restrict__ c_o)
{
    int b = blockIdx.x;
    const float* in; short* out; int i;
    if (b < NB_XS)            { in = xs; out = xs_o; i = b * 256 + threadIdx.x; }
    else if (b < NB_XS + NB_W){ in = w;  out = w_o;  i = (b - NB_XS) * 256 + threadIdx.x; }
    else                      { in = c;  out = c_o;  i = (b - NB_XS - NB_W) * 256 + threadIdx.x; }
    float4 v = ((const float4*)in)[i];
    short4v s;
    s.x = f2bf(v.x); s.y = f2bf(v.y); s.z = f2bf(v.z); s.w = f2bf(v.w);
    ((short4v*)out)[i] = s;
}

// ---------- bf16 GEMM, C[m][n] = sum_k A[m][k]*B[n][k] (both K-contiguous) ----------
// 256x256 tile, BK=64, 512 threads = 8 waves (2M x 4N), wave => 128x64 output
// (quadrants mh in {0,1} row-halves, nh in {0,1} col-halves).
// R6 EVEN-READ schedule (best measured, 156.7 us): per K-tile 4 phases, each
// operand ds_read exactly ONE phase ahead (reads/phase 4/8/4/8), stages
// front-loaded 2/2/0/0, counted gates VMC2/VMC2/-/VMC1 (never 0 in loop).
// XOR-8 slot swizzle both-sides (0 bank conflicts). XCD-chunk block swizzle
// (FETCH 350->170 MB, both verified).
// FUSE==0: store bf16 C + FUSED scan_pass1 (per-chunk weighted sums from fp32
// acc -> blockLast). FUSE==1: store fp32 C + xs*dskip.

#define BAR   __builtin_amdgcn_s_barrier()
#define PRIO1 __builtin_amdgcn_s_setprio(1)
#define PRIO0 __builtin_amdgcn_s_setprio(0)
#define VMC2  asm volatile("s_waitcnt vmcnt(2)" ::: "memory")
#define VMC1  asm volatile("s_waitcnt vmcnt(1)" ::: "memory")
#define VMC0  asm volatile("s_waitcnt vmcnt(0)" ::: "memory")

// stage one 128x64 half-tile (16 KiB): 2 x global_load_lds(16B) per thread.
// LDS dest linear; global source slot XOR-swizzled (involution s^(row&7)).
#define STAGE_A(b, h, t) do { \
    const short* _s = Abase + (size_t)(h) * 128 * K + (size_t)(t) * 64; \
    __builtin_amdgcn_global_load_lds(_s + gOff0, &As[b][h][c0 * 8], 16, 0, 0); \
    __builtin_amdgcn_global_load_lds(_s + gOff1, &As[b][h][c1 * 8], 16, 0, 0); \
} while (0)
#define STAGE_B(b, h, t) do { \
    const short* _s = Bbase + (size_t)(h) * 128 * K + (size_t)(t) * 64; \
    __builtin_amdgcn_global_load_lds(_s + gOff0, &Bs[b][h][c0 * 8], 16, 0, 0); \
    __builtin_amdgcn_global_load_lds(_s + gOff1, &Bs[b][h][c1 * 8], 16, 0, 0); \
} while (0)

// fragment reads: logical slot (ks*4+quad), physical slot XOR (row&7) = sx
#define READ_A8(dst, b, mh) \
    _Pragma("unroll") \
    for (int mi = 0; mi < 4; mi++) { \
        _Pragma("unroll") \
        for (int ks = 0; ks < 2; ks++) \
            dst[mi][ks] = *(const short8*)&As[b][mh][(arow + mi * 16) * 64 + \
                                                     ((((ks << 2) | quad) ^ sx) << 3)]; \
    }
#define READ_B4(dst, b, nh) \
    _Pragma("unroll") \
    for (int ni = 0; ni < 2; ni++) { \
        _Pragma("unroll") \
        for (int ks = 0; ks < 2; ks++) \
            dst[ni][ks] = *(const short8*)&Bs[b][nh][(brow + ni * 16) * 64 + \
                                                     ((((ks << 2) | quad) ^ sx) << 3)]; \
    }
#define MMA(mh, nh, Aset, Bset) \
    _Pragma("unroll") \
    for (int mi = 0; mi < 4; mi++) { \
        _Pragma("unroll") \
        for (int ni = 0; ni < 2; ni++) { \
            acc[mh][nh][mi][ni] = __builtin_amdgcn_mfma_f32_16x16x32_bf16( \
                Aset[mi][0], Bset[ni][0], acc[mh][nh][mi][ni], 0, 0, 0); \
            acc[mh][nh][mi][ni] = __builtin_amdgcn_mfma_f32_16x16x32_bf16( \
                Aset[mi][1], Bset[ni][1], acc[mh][nh][mi][ni], 0, 0, 0); \
        } \
    }

template<int FUSE>
__global__ __launch_bounds__(512, 2)
void gemm_bt(const short* __restrict__ A, const short* __restrict__ B,
             short* __restrict__ Cbf, float* __restrict__ Cf,
             const float* __restrict__ xs, const float* __restrict__ dskip,
             const float* __restrict__ lamv, float* __restrict__ blkl)
{
    constexpr int K  = DIM;        // 2048
    constexpr int NT = K / 64;     // 32 K-tiles

    __shared__ alignas(16) short As[2][2][128 * 64];   // [buf][half][row*64+slot*8]
    __shared__ alignas(16) short Bs[2][2][128 * 64];

    const int tid = threadIdx.x;
    // XCD-chunk swizzle (bijective on the 8x64 grid): hw xcd = raw%8 owns an
    // 8x8 super-tile (rows 8*xcd..8*xcd+7, all 8 cols).
    const int raw  = blockIdx.y * gridDim.x + blockIdx.x;
    const int xcd  = raw & 7;
    const int slot = raw >> 3;                 // 0..63
    const int m0   = ((xcd << 3) | (slot >> 3)) * 256;
    const int n0   = (slot & 7) * 256;

    const int lane = tid & 63;
    const int wv   = tid >> 6;
    const int wrow = wv >> 2;           // 0..1
    const int wcol = wv & 3;            // 0..3
    const int l16  = lane & 15;
    const int quad = lane >> 4;
    const int sx   = l16 & 7;
    const int arow = wrow * 64 + l16;   // local row in A half-region
    const int brow = wcol * 32 + l16;   // local row in B half-region

    // staging constants: chunks c0, c1 of each half-tile (1024 x 16B chunks)
    const int c0 = tid, c1 = tid + 512;
    const int r0 = c0 >> 3, r1 = c1 >> 3;
    const size_t gOff0 = (size_t)r0 * K + (size_t)((((c0 & 7) ^ (r0 & 7))) * 8);
    const size_t gOff1 = (size_t)r1 * K + (size_t)((((c1 & 7) ^ (r1 & 7))) * 8);
    const short* Abase = A + (size_t)m0 * K;
    const short* Bbase = B + (size_t)n0 * K;

    short8  aE[4][2], aO[4][2], bE[2][2], bO[2][2];
    floatx4 acc[2][2][4][2] = {};   // [mh][nh][mi][ni]

    // ---- prologue: buf0 <- tile0. Order {Ah0,Bh0,Bh1} then Ah1; drain first 3.
    STAGE_A(0, 0, 0); STAGE_B(0, 0, 0); STAGE_B(0, 1, 0);
    STAGE_A(0, 1, 0);
    VMC1;                    // queue: {Ah1(0)}  == steady-state entry invariant
    BAR;
    READ_A8(aE, 0, 0); READ_B4(bE, 0, 0);   // pre-read tile0 quadrant(0,0) operands

    for (int i = 0; i < NT / 2; ++i) {
        const int t1 = 2 * i + 1;
        const int t2 = (2 * i + 2) & (NT - 1);   // wrap: tail stages harmless

        // ======== tile even (buf0); stages -> buf1 <- t1 ========
        // p0: mma(0,0); read bO (Bh1, cur); stage Ah0,Bh0(next). VMC2 drains Ah1(cur).
        READ_B4(bO, 0, 1);
        STAGE_A(1, 0, t1); STAGE_B(1, 0, t1);
        PRIO1; MMA(0, 0, aE, bE); PRIO0;
        VMC2;
        BAR;
        // p1: mma(0,1); read aO (Ah1, cur); stage Bh1,Ah1(next). VMC2 drains Ah0,Bh0(next).
        READ_A8(aO, 0, 1);
        STAGE_B(1, 1, t1); STAGE_A(1, 1, t1);
        PRIO1; MMA(0, 1, aE, bO); PRIO0;
        VMC2;
        BAR;
        // p2: mma(1,0); then re-read bE from NEXT buf (Bh0(next), gated at p1).
        PRIO1; MMA(1, 0, aO, bE); PRIO0;
        READ_B4(bE, 1, 0);
        BAR;
        // p3: mma(1,1); re-read aE from NEXT buf (Ah0(next), gated at p1).
        //     VMC1 drains Bh1(next), leaves Ah1(next) in flight (entry invariant).
        PRIO1; MMA(1, 1, aO, bO); PRIO0;
        READ_A8(aE, 1, 0);
        VMC1;
        BAR;

        // ======== tile odd (buf1); stages -> buf0 <- t2 ========
        READ_B4(bO, 1, 1);
        STAGE_A(0, 0, t2); STAGE_B(0, 0, t2);
        PRIO1; MMA(0, 0, aE, bE); PRIO0;
        VMC2;
        BAR;

        READ_A8(aO, 1, 1);
        STAGE_B(0, 1, t2); STAGE_A(0, 1, t2);
        PRIO1; MMA(0, 1, aE, bO); PRIO0;
        VMC2;
        BAR;

        PRIO1; MMA(1, 0, aO, bE); PRIO0;
        READ_B4(bE, 0, 0);
        BAR;

        PRIO1; MMA(1, 1, aO, bO); PRIO0;
        READ_A8(aE, 0, 0);
        VMC1;
        BAR;
    }
    VMC0;   // no LDS-DMA may outlive this workgroup

    // ---- epilogue: C row = m0+wrow*64+mh*128+mi*16+quad*4+r, col = n0+wcol*32+nh*128+ni*16+l16
    if (FUSE == 0) {
        #pragma unroll
        for (int mh = 0; mh < 2; mh++)
        #pragma unroll
        for (int mi = 0; mi < 4; mi++) {
            const int rb = m0 + wrow * 64 + mh * 128 + mi * 16 + quad * 4;
            #pragma unroll
            for (int nh = 0; nh < 2; nh++)
            #pragma unroll
            for (int ni = 0; ni < 2; ni++) {
                const int cc = n0 + wcol * 32 + nh * 128 + ni * 16 + l16;
                #pragma unroll
                for (int r = 0; r < 4; r++)
                    Cbf[(size_t)(rb + r) * DIM + cc] = f2bf(acc[mh][nh][mi][ni][r]);
            }
        }
        // ---- fused scan_pass1: blockLast[chunk][col] = sum_i lam^(127-i) * acc
        // chunk = m0/128 + mh; row-in-chunk = wrow*64 + mi*16 + quad*4 + r.
        // weight = lam^(127-row) = (l^4)^(k3 + 4*(3-mi)) * l^(3-r),
        // k3 = 19 - 16*wrow - quad  (>= 0).
        float Pacc[2][2][2];   // [mh][nh][ni]
        #pragma unroll
        for (int nh = 0; nh < 2; nh++)
        #pragma unroll
        for (int ni = 0; ni < 2; ni++) {
            const int cc = n0 + wcol * 32 + nh * 128 + ni * 16 + l16;
            const float l = lamv[cc];
            const float l2 = l * l, l4 = l2 * l2, l8 = l4 * l4;
            const float l16p = l8 * l8, l32 = l16p * l16p, l64 = l32 * l32;
            const int k3 = 19 - 16 * wrow - quad;
            float q = 1.f;
            q = (k3 & 1)  ? q * l4   : q;
            q = (k3 & 2)  ? q * l8   : q;
            q = (k3 & 4)  ? q * l16p : q;
            q = (k3 & 8)  ? q * l32  : q;
            q = (k3 & 16) ? q * l64  : q;
            #pragma unroll
            for (int mh = 0; mh < 2; mh++) {
                float s = 0.f, qq = q;
                #pragma unroll
                for (int mi = 3; mi >= 0; --mi) {
                    floatx4 a = acc[mh][nh][mi][ni];
                    float inner = fmaf(fmaf(fmaf(a[0], l, a[1]), l, a[2]), l, a[3]);
                    s = fmaf(qq, inner, s);
                    qq *= l16p;
                }
                Pacc[mh][nh][ni] = s;
            }
        }
        // cross-quad (shfl) then cross-wave (LDS) reduction
        float* Pl = (float*)&As[0][0][0];    // [wrow][mh][256 cols], 4 KB
        #pragma unroll
        for (int mh = 0; mh < 2; mh++)
        #pragma unroll
        for (int nh = 0; nh < 2; nh++)
        #pragma unroll
        for (int ni = 0; ni < 2; ni++) {
            float v = Pacc[mh][nh][ni];
            v += __shfl_xor(v, 16);
            v += __shfl_xor(v, 32);
            if (lane < 16)
                Pl[wrow * 512 + mh * 256 + (wcol * 32 + nh * 128 + ni * 16 + l16)] = v;
        }
        __syncthreads();
        {
            const int mh = tid >> 8, cl = tid & 255;
            float v = Pl[mh * 256 + cl] + Pl[512 + mh * 256 + cl];
            blkl[(size_t)((m0 >> 7) + mh) * DIM + (n0 + cl)] = v;
        }
    } else {
        float dsk[2][2];
        #pragma unroll
        for (int nh = 0; nh < 2; nh++)
        #pragma unroll
        for (int ni = 0; ni < 2; ni++)
            dsk[nh][ni] = dskip[n0 + wcol * 32 + nh * 128 + ni * 16 + l16];
        #pragma unroll
        for (int mh = 0; mh < 2; mh++)
        #pragma unroll
        for (int mi = 0; mi < 4; mi++) {
            const int rb = m0 + wrow * 64 + mh * 128 + mi * 16 + quad * 4;
            #pragma unroll
            for (int nh = 0; nh < 2; nh++)
            #pragma unroll
            for (int ni = 0; ni < 2; ni++) {
                const int cc = n0 + wcol * 32 + nh * 128 + ni * 16 + l16;
                #pragma unroll
                for (int r = 0; r < 4; r++) {
                    size_t idx = (size_t)(rb + r) * DIM + cc;
                    Cf[idx] = acc[mh][nh][mi][ni][r] + xs[idx] * dsk[nh][ni];
                }
            }
        }
    }
}

// ---------- scan pass 2+3 fused: per-block self-computed carry, then chunk scan ----------
// carry[chunk][n] = sum_{j<chunk} (lam^128)^(chunk-1-j) * blkl[j][n]  (Horner over
// the L2-resident 1 MiB blkl); then apply carry + in-place bf16 scan over bxh.
__global__ void scan_pass23(short* __restrict__ bxh, const float* __restrict__ lam,
                            const float* __restrict__ blkl)
{
    int q     = blockIdx.x * 256 + threadIdx.x;   // 4-col group id
    int n     = q * 4;
    int chunk = blockIdx.y;
    float4 lm = *(const float4*)&lam[n];
    float p0 = lm.x, p1 = lm.y, p2 = lm.z, p3 = lm.w;
    #pragma unroll
    for (int i = 0; i < 7; i++) { p0 *= p0; p1 *= p1; p2 *= p2; p3 *= p3; }  // lam^128
    float h0 = 0.f, h1 = 0.f, h2 = 0.f, h3 = 0.f;
    #pragma unroll 4
    for (int j = 0; j < chunk; ++j) {
        float4 s = *(const float4*)&blkl[(size_t)j * DIM + n];
        h0 = fmaf(p0, h0, s.x);
        h1 = fmaf(p1, h1, s.y);
        h2 = fmaf(p2, h2, s.z);
        h3 = fmaf(p3, h3, s.w);
    }
    uint2* p = (uint2*)(bxh + (size_t)chunk * CHUNK * DIM) + q;
    #pragma unroll 16
    for (int i = 0; i < CHUNK; i++) {
        uint2 v = p[(size_t)i * (DIM / 4)];
        h0 = fmaf(lm.x, h0, bf2f((short)(v.x & 0xffffu)));
        h1 = fmaf(lm.y, h1, bf2f((short)(v.x >> 16)));
        h2 = fmaf(lm.z, h2, bf2f((short)(v.y & 0xffffu)));
        h3 = fmaf(lm.w, h3, bf2f((short)(v.y >> 16)));
        uint2 o;
        o.x = (unsigned)(unsigned short)f2bf(h0) | ((unsigned)(unsigned short)f2bf(h1) << 16);
        o.y = (unsigned)(unsigned short)f2bf(h2) | ((unsigned)(unsigned short)f2bf(h3) << 16);
        p[(size_t)i * (DIM / 4)] = o;
    }
}

extern "C" void kernel_launch(void* const* d_in, const int* in_sizes, int n_in,
                              void* d_out, int out_size, void* d_ws, size_t ws_size,
                              hipStream_t stream)
{
    const float* xs    = (const float*)d_in[0];
    const float* lam   = (const float*)d_in[1];
    const float* w_in  = (const float*)d_in[2];
    const float* c_out = (const float*)d_in[3];
    const float* dskip = (const float*)d_in[4];
    float* out = (float*)d_out;

    // ws layout:
    //   [0,   64M) : bx / hs  bf16  [SEQ][DIM]
    //   [64M, 72M) : w_in     bf16  [DIM][DIM]
    //   [72M, 80M) : c_out    bf16  [DIM][DIM]
    char*  ws    = (char*)d_ws;
    short* bxh   = (short*)ws;
    short* w_bf  = (short*)(ws + (size_t)64 * 1024 * 1024);
    short* c_bf  = (short*)(ws + (size_t)72 * 1024 * 1024);
    // xs_bf16 in front 64 MiB of d_out (dead before final GEMM writes it);
    // chunk sums (1 MiB) at d_out+100 MiB (dead until final GEMM write).
    short* xs_bf = (short*)d_out;
    float* blkl  = (float*)((char*)d_out + (size_t)100 * 1024 * 1024);

    cast3_kernel<<<NB_XS + 2 * NB_W, 256, 0, stream>>>(xs, xs_bf, w_in, w_bf, c_out, c_bf);

    dim3 ggrid(DIM / 256, SEQ / 256);   // (8, 64)
    gemm_bt<0><<<ggrid, 512, 0, stream>>>(xs_bf, w_bf, bxh, nullptr, nullptr, nullptr,
                                          lam, blkl);

    dim3 sgrid(DIM / 1024, NCHUNK);     // (2, 128)
    scan_pass23<<<sgrid, 256, 0, stream>>>(bxh, lam, blkl);

    gemm_bt<1><<<ggrid, 512, 0, stream>>>(bxh, c_bf, nullptr, out, xs, dskip,
                                          nullptr, nullptr);
}